// Round 22
// baseline (42.049 us; speedup 1.0000x reference)
//
#include <hip/hip_runtime.h>
#include <hip/hip_bf16.h>

#define B_   8
#define LQ_  128
#define LM_  512
#define D_   512
#define H_   256
#define MASKVAL -1e24f
#define PRESCALE 2.88539008177792681f  // 2*log2(e): exp2(PRESCALE*x) = e^(2x)

typedef __attribute__((ext_vector_type(8))) short bf16x8;
typedef __attribute__((ext_vector_type(8))) ushort ushort8;
typedef __attribute__((ext_vector_type(4))) float f32x4;

__device__ __forceinline__ ushort f2bf(float x) {
    return __builtin_bit_cast(ushort, __float2bfloat16(x));
}
__device__ __forceinline__ float bf2f(ushort u) {
    return __builtin_bit_cast(float, (unsigned)u << 16);
}

// ---------------- MFMA projection GEMM, 64x64 tile ----------------
// 4 waves x (2x2) 16x16 frags -> 8 MFMA per wave per k-tile: 4x the MFMA
// density and half the staging traffic of the old 32x32 version.
// qp: [1024][256] f32 = Eq;  kT: [32 h8][4096 m][8] bf16 = Ek.
#define QBM 64
#define QBN 64
#define QLDK 72   // padded k-stride (ushorts) = 144 B

__global__ __launch_bounds__(256) void proj_mfma(
    const float* __restrict__ query, const float* __restrict__ memory,
    const float* __restrict__ Wq, const float* __restrict__ Wm,
    const float* __restrict__ bq,
    float* __restrict__ qp, ushort* __restrict__ kT)
{
    __shared__ ushort As[QBM][QLDK];   // X rows x k
    __shared__ ushort Bs[QBN][QLDK];   // W^T: n x k

    const int mtile = blockIdx.x % 80;   // 16 q-tiles + 64 k-tiles
    const int ntile = blockIdx.x / 80;   // 0..3
    const int n0 = ntile * QBN;
    const bool is_q = (mtile < 16);
    const float* X = is_q ? (query  + (size_t)mtile * QBM * D_)
                          : (memory + (size_t)(mtile - 16) * QBM * D_);
    const float* W = is_q ? Wq : Wm;

    const int t = threadIdx.x;
    const int lane = t & 63, w = t >> 6;
    const int wm = (w & 1) * 32, wn = (w >> 1) * 32;
    const int ar  = t >> 4;   // staging row base (16/pass)
    const int akq = t & 15;   // k-quad
    const int frow = lane & 15;
    const int fkof = (lane >> 4) * 8;

    f32x4 acc[2][2];
#pragma unroll
    for (int i = 0; i < 2; ++i)
#pragma unroll
        for (int j = 0; j < 2; ++j) acc[i][j] = (f32x4){0.f, 0.f, 0.f, 0.f};

    for (int k0 = 0; k0 < D_; k0 += 64) {
        // stage X: 64 rows x 64 k, f32 -> bf16
#pragma unroll
        for (int p = 0; p < 4; ++p) {
            const int row = ar + p * 16;
            const float4 x4 = *(const float4*)(X + (size_t)row * D_ + k0 + akq * 4);
            ushort4 u4;
            u4.x = f2bf(x4.x); u4.y = f2bf(x4.y); u4.z = f2bf(x4.z); u4.w = f2bf(x4.w);
            *(ushort4*)&As[row][akq * 4] = u4;
        }
        // stage W: 64 k x 64 n -> Bs[n][k] transposed
#pragma unroll
        for (int p = 0; p < 4; ++p) {
            const int L  = t + p * 256;    // 0..1023
            const int kk = L >> 4;         // 0..63
            const int f4 = L & 15;         // n-quad 0..15
            const float4 w4 = *(const float4*)(W + (size_t)(k0 + kk) * H_ + n0 + f4 * 4);
            Bs[f4 * 4 + 0][kk] = f2bf(w4.x);
            Bs[f4 * 4 + 1][kk] = f2bf(w4.y);
            Bs[f4 * 4 + 2][kk] = f2bf(w4.z);
            Bs[f4 * 4 + 3][kk] = f2bf(w4.w);
        }
        __syncthreads();
#pragma unroll
        for (int ks = 0; ks < 64; ks += 32) {
            bf16x8 a0 = *(const bf16x8*)&As[wm + frow][ks + fkof];
            bf16x8 a1 = *(const bf16x8*)&As[wm + 16 + frow][ks + fkof];
            bf16x8 b0 = *(const bf16x8*)&Bs[wn + frow][ks + fkof];
            bf16x8 b1 = *(const bf16x8*)&Bs[wn + 16 + frow][ks + fkof];
            acc[0][0] = __builtin_amdgcn_mfma_f32_16x16x32_bf16(a0, b0, acc[0][0], 0, 0, 0);
            acc[0][1] = __builtin_amdgcn_mfma_f32_16x16x32_bf16(a0, b1, acc[0][1], 0, 0, 0);
            acc[1][0] = __builtin_amdgcn_mfma_f32_16x16x32_bf16(a1, b0, acc[1][0], 0, 0, 0);
            acc[1][1] = __builtin_amdgcn_mfma_f32_16x16x32_bf16(a1, b1, acc[1][1], 0, 0, 0);
        }
        __syncthreads();
    }

    const int lane16 = lane & 15;
    const int r4 = (lane >> 4) * 4;        // C/D row group (verified map)
    if (is_q) {
        float* out = qp + (size_t)mtile * QBM * H_;
#pragma unroll
        for (int i = 0; i < 2; ++i)
#pragma unroll
            for (int j = 0; j < 2; ++j) {
                const int col = n0 + wn + j * 16 + lane16;
                const float bias = bq[col];
#pragma unroll
                for (int r = 0; r < 4; ++r)
                    out[(size_t)(wm + i * 16 + r4 + r) * H_ + col] =
                        __builtin_amdgcn_exp2f((acc[i][j][r] + bias) * PRESCALE);
            }
    } else {
        const int mbase = (mtile - 16) * QBM + wm;
#pragma unroll
        for (int i = 0; i < 2; ++i)
#pragma unroll
            for (int j = 0; j < 2; ++j) {
                const int h = n0 + wn + j * 16 + lane16;
                ushort* kdst = kT + (size_t)(h >> 3) * 4096 * 8 + (h & 7);
#pragma unroll
                for (int r = 0; r < 4; ++r) {
                    const int m = mbase + i * 16 + r4 + r;
                    kdst[(size_t)m * 8] =
                        f2bf(__builtin_amdgcn_exp2f(acc[i][j][r] * PRESCALE));
                }
            }
    }
}

// ---------------- scores + softmax (R19, frozen best) ----------------
__global__ __launch_bounds__(512, 4) void score_softmax(
    const float* __restrict__ qp,      // [1024][256] = Eq f32
    const ushort* __restrict__ kT,     // [32][4096][8] = Ek bf16
    const int*   __restrict__ mask,    // [8][512]
    const float* __restrict__ v,       // [256]
    float* __restrict__ out_w,         // [1024][512]
    ushort* __restrict__ wbf)          // [1024][512] bf16 weights
{
    __shared__ float scores[2][512];

    const int t = threadIdx.x;
    const int b  = blockIdx.x & 7;
    const int qg = blockIdx.x >> 3;    // 0..63
    const int rowbase = b * LQ_ + qg * 2;
    const int w = t >> 6, lane = t & 63;

    {
        const int m = t;               // 512 threads = 512 m
        const ushort* kbase = kT + ((size_t)b * 512 + m) * 8;
        const float* q0r = qp + (size_t)(rowbase + 0) * 256;
        const float* q1r = qp + (size_t)(rowbase + 1) * 256;
        float acc0 = 0.f, acc1 = 0.f;
#define QUAD(ACC, SQ, K, SV) { \
        const float u_ = fmaf(SQ.x, K.x, 1.f); \
        const float w_ = fmaf(SQ.y, K.y, 1.f); \
        const float y_ = fmaf(SQ.z, K.z, 1.f); \
        const float z_ = fmaf(SQ.w, K.w, 1.f); \
        const float d12_ = u_ * w_, d34_ = y_ * z_; \
        const float n12_ = fmaf(SV.y, u_, SV.x * w_); \
        const float n34_ = fmaf(SV.w, y_, SV.z * z_); \
        const float N_ = fmaf(n12_, d34_, n34_ * d12_); \
        ACC = fmaf(N_, __builtin_amdgcn_rcpf(d12_ * d34_), ACC); }
#pragma unroll 4
        for (int h8 = 0; h8 < 32; ++h8) {
            const ushort8 ku = *(const ushort8*)(kbase + (size_t)h8 * 32768);
            const float4 ka = {bf2f(ku[0]), bf2f(ku[1]), bf2f(ku[2]), bf2f(ku[3])};
            const float4 kb = {bf2f(ku[4]), bf2f(ku[5]), bf2f(ku[6]), bf2f(ku[7])};
            const float4 va = *(const float4*)(v + h8 * 8);
            const float4 vb = *(const float4*)(v + h8 * 8 + 4);
            const float4 s0a = *(const float4*)(q0r + h8 * 8);
            const float4 s0b = *(const float4*)(q0r + h8 * 8 + 4);
            const float4 s1a = *(const float4*)(q1r + h8 * 8);
            const float4 s1b = *(const float4*)(q1r + h8 * 8 + 4);
            QUAD(acc0, s0a, ka, va)
            QUAD(acc0, s0b, kb, vb)
            QUAD(acc1, s1a, ka, va)
            QUAD(acc1, s1b, kb, vb)
        }
#undef QUAD
        scores[0][m] = -2.f * acc0;
        scores[1][m] = -2.f * acc1;
    }
    __syncthreads();

    if (w < 2) {
        const int q = w, row = rowbase + q;
        float s[8], e[8];
        float mx = -INFINITY;
#pragma unroll
        for (int k = 0; k < 8; ++k) {
            const int m = lane + 64 * k;
            s[k] = mask[b * 512 + m] ? MASKVAL : scores[q][m];
            mx = fmaxf(mx, s[k]);
        }
#pragma unroll
        for (int off = 32; off >= 1; off >>= 1) mx = fmaxf(mx, __shfl_xor(mx, off));
        float sum = 0.0f;
#pragma unroll
        for (int k = 0; k < 8; ++k) {
            e[k] = __builtin_amdgcn_exp2f((s[k] - mx) * 1.44269504088896341f);
            sum += e[k];
        }
#pragma unroll
        for (int off = 32; off >= 1; off >>= 1) sum += __shfl_xor(sum, off);
        const float rs = __builtin_amdgcn_rcpf(sum);
#pragma unroll
        for (int k = 0; k < 8; ++k) {
            const int m = lane + 64 * k;
            const float wt = e[k] * rs;
            out_w[(size_t)row * 512 + m] = wt;
            wbf[(size_t)row * 512 + m] = f2bf(wt);
        }
    }
}

// ---------------- PV via MFMA (R16/R19 staged version, frozen) ----------------
#define PBM 32
#define PBN 32
#define PBK 64
#define PLDK 88

__global__ __launch_bounds__(256) void pv_mfma(
    const ushort* __restrict__ wbf,    // [1024][512] bf16
    const float* __restrict__ memory,  // [8][512][512]
    float* __restrict__ out_wm)        // [1024][512]
{
    __shared__ ushort As[PBM][PLDK];
    __shared__ ushort Bs[PBN][PLDK];

    const int b    = blockIdx.x & 7;
    const int rest = blockIdx.x >> 3;  // 0..63
    const int mt   = rest & 3;         // q-tile 0..3
    const int nt   = rest >> 2;        // d-tile 0..15
    const int n0   = nt * PBN;
    const ushort* A = wbf + ((size_t)b * LQ_ + mt * PBM) * 512;
    const float*  Bm = memory + (size_t)b * 512 * 512;

    const int t = threadIdx.x;
    const int lane = t & 63, w = t >> 6;
    const int wm = (w & 1) * 16, wn = (w >> 1) * 16;
    const int ar  = t >> 4;
    const int akq = t & 15;
    const int frow = lane & 15;
    const int fkof = (lane >> 4) * 8;

    f32x4 acc = {0.f, 0.f, 0.f, 0.f};

    for (int k0 = 0; k0 < 512; k0 += PBK) {
#pragma unroll
        for (int p = 0; p < 2; ++p) {
            const int row = ar + p * 16;
            *(ushort4*)&As[row][akq * 4] =
                *(const ushort4*)(A + (size_t)row * 512 + k0 + akq * 4);
        }
#pragma unroll
        for (int p = 0; p < 2; ++p) {
            const int L  = t + p * 256;
            const int kk = L >> 3;
            const int f4 = L & 7;
            const float4 w4 = *(const float4*)(Bm + (size_t)(k0 + kk) * 512 + n0 + f4 * 4);
            Bs[f4 * 4 + 0][kk] = f2bf(w4.x);
            Bs[f4 * 4 + 1][kk] = f2bf(w4.y);
            Bs[f4 * 4 + 2][kk] = f2bf(w4.z);
            Bs[f4 * 4 + 3][kk] = f2bf(w4.w);
        }
        __syncthreads();
#pragma unroll
        for (int ks = 0; ks < PBK; ks += 32) {
            bf16x8 a = *(const bf16x8*)&As[wm + frow][ks + fkof];
            bf16x8 b2 = *(const bf16x8*)&Bs[wn + frow][ks + fkof];
            acc = __builtin_amdgcn_mfma_f32_16x16x32_bf16(a, b2, acc, 0, 0, 0);
        }
        __syncthreads();
    }

    const int col  = n0 + wn + (lane & 15);
    const int rloc = wm + (lane >> 4) * 4;
    float* out = out_wm + ((size_t)b * LQ_ + mt * PBM) * 512;
#pragma unroll
    for (int r = 0; r < 4; ++r)
        out[(size_t)(rloc + r) * 512 + col] = acc[r];
}

extern "C" void kernel_launch(void* const* d_in, const int* in_sizes, int n_in,
                              void* d_out, int out_size, void* d_ws, size_t ws_size,
                              hipStream_t stream) {
    const float* query  = (const float*)d_in[0];
    const float* memory = (const float*)d_in[1];
    const int*   mask   = (const int*)  d_in[2];
    const float* Wq     = (const float*)d_in[3];
    const float* bq     = (const float*)d_in[4];
    const float* Wm     = (const float*)d_in[5];
    const float* v      = (const float*)d_in[6];

    float* out_wm = (float*)d_out;                         // [1024][512]
    float* out_w  = out_wm + (size_t)B_ * LQ_ * D_;        // [1024][512]

    float*  qp  = (float*)d_ws;                            // [1024][256] f32 = Eq
    ushort* kT  = (ushort*)(qp + (size_t)B_ * LQ_ * H_);   // [32][4096][8] bf16 = Ek
    ushort* wbf = kT + (size_t)32 * 4096 * 8;              // [1024][512] bf16

    hipLaunchKernelGGL(proj_mfma, dim3(80 * (H_ / QBN)), dim3(256), 0, stream,
                       query, memory, Wq, Wm, bq, qp, kT);
    hipLaunchKernelGGL(score_softmax, dim3(B_ * (LQ_ / 2)), dim3(512), 0, stream,
                       qp, kT, mask, v, out_w, wbf);
    hipLaunchKernelGGL(pv_mfma, dim3(8 * 64), dim3(256), 0, stream,
                       wbf, memory, out_wm);
}

// Round 23
// 38.687 us; speedup vs baseline: 1.0869x; 1.0869x over previous
//
#include <hip/hip_runtime.h>
#include <hip/hip_bf16.h>

#define B_   8
#define LQ_  128
#define LM_  512
#define D_   512
#define H_   256
#define MASKVAL -1e24f
#define PRESCALE 2.88539008177792681f  // 2*log2(e): exp2(PRESCALE*x) = e^(2x)

typedef __attribute__((ext_vector_type(8))) short bf16x8;
typedef __attribute__((ext_vector_type(8))) ushort ushort8;
typedef __attribute__((ext_vector_type(4))) float f32x4;

__device__ __forceinline__ ushort f2bf(float x) {
    return __builtin_bit_cast(ushort, __float2bfloat16(x));
}
__device__ __forceinline__ float bf2f(ushort u) {
    return __builtin_bit_cast(float, (unsigned)u << 16);
}

// ---------------- MFMA projection GEMM (bf16 inputs, f32 accum) ----------------
// qp: row-major [1024][256] f32, holds Eq = exp2(PRESCALE*(q@Wq+bq))
// kT:  [32 h8][4096 m][8] bf16, holds Ek — one lane b128 = 8 h values
#define PBM 32
#define PBN 32
#define PBK 64
#define PLDK 88

__global__ __launch_bounds__(256) void proj_mfma(
    const float* __restrict__ query, const float* __restrict__ memory,
    const float* __restrict__ Wq, const float* __restrict__ Wm,
    const float* __restrict__ bq,
    float* __restrict__ qp, ushort* __restrict__ kT)
{
    __shared__ ushort As[PBM][PLDK];
    __shared__ ushort Bs[PBN][PLDK];
    __shared__ float  T[PBM][33];

    const int mtile = blockIdx.x % 160;
    const int ntile = blockIdx.x / 160;
    const int n0 = ntile * PBN;
    const bool is_q = (mtile < 32);
    const float* X = is_q ? (query  + (size_t)mtile * PBM * D_)
                          : (memory + (size_t)(mtile - 32) * PBM * D_);
    const float* W = is_q ? Wq : Wm;

    const int t = threadIdx.x;
    const int lane = t & 63, w = t >> 6;
    const int wm = (w & 1) * 16, wn = (w >> 1) * 16;
    const int ar  = t >> 4;
    const int akq = t & 15;
    const int frow = lane & 15;
    const int fkof = (lane >> 4) * 8;

    f32x4 acc = {0.f, 0.f, 0.f, 0.f};

    for (int k0 = 0; k0 < D_; k0 += PBK) {
#pragma unroll
        for (int p = 0; p < 2; ++p) {
            const int row = ar + p * 16;
            const float4 x4 = *(const float4*)(X + (size_t)row * D_ + k0 + akq * 4);
            ushort4 u4;
            u4.x = f2bf(x4.x); u4.y = f2bf(x4.y); u4.z = f2bf(x4.z); u4.w = f2bf(x4.w);
            *(ushort4*)&As[row][akq * 4] = u4;
        }
#pragma unroll
        for (int p = 0; p < 2; ++p) {
            const int L  = t + p * 256;
            const int kk = L >> 3;
            const int f4 = L & 7;
            const float4 w4 = *(const float4*)(W + (size_t)(k0 + kk) * H_ + n0 + f4 * 4);
            Bs[f4 * 4 + 0][kk] = f2bf(w4.x);
            Bs[f4 * 4 + 1][kk] = f2bf(w4.y);
            Bs[f4 * 4 + 2][kk] = f2bf(w4.z);
            Bs[f4 * 4 + 3][kk] = f2bf(w4.w);
        }
        __syncthreads();
#pragma unroll
        for (int ks = 0; ks < PBK; ks += 32) {
            bf16x8 a = *(const bf16x8*)&As[wm + frow][ks + fkof];
            bf16x8 b = *(const bf16x8*)&Bs[wn + frow][ks + fkof];
            acc = __builtin_amdgcn_mfma_f32_16x16x32_bf16(a, b, acc, 0, 0, 0);
        }
        __syncthreads();
    }

    const int lane16 = lane & 15;
    const int rloc = wm + (lane >> 4) * 4;
    if (is_q) {
        const int col = n0 + wn + lane16;
        const float bias = bq[col];
        float* out = qp + (size_t)mtile * PBM * H_;
#pragma unroll
        for (int r = 0; r < 4; ++r)
            out[(size_t)(rloc + r) * H_ + col] =
                __builtin_amdgcn_exp2f((acc[r] + bias) * PRESCALE);
    } else {
#pragma unroll
        for (int r = 0; r < 4; ++r)
            T[rloc + r][wn + lane16] = __builtin_amdgcn_exp2f(acc[r] * PRESCALE);
        __syncthreads();
        const int m_local = t & 31;
        const int hq = t >> 5;             // h-quad 0..7 (local h = hq*4..+3)
        const int h0 = hq * 4;
        const int gm = (mtile - 32) * 32 + m_local;
        ushort4 u4;
        u4.x = f2bf(T[m_local][h0 + 0]);
        u4.y = f2bf(T[m_local][h0 + 1]);
        u4.z = f2bf(T[m_local][h0 + 2]);
        u4.w = f2bf(T[m_local][h0 + 3]);
        // kT[h8][m][8]: h8 = (n0+h0)>>3; slot = (hq&1)*4
        ushort* dst = kT + ((size_t)((n0 >> 3) + (hq >> 1)) * 4096 + gm) * 8 + (hq & 1) * 4;
        *(ushort4*)dst = u4;
    }
}

// ---------------- scores + softmax ----------------
// 512 blocks x 512 thr. Block = (b, 2 q); lane = m. kT bf16: one b128 load
// delivers 8 h -> 32 iterations, half the VMEM instrs / L2 bytes of f32 kT.
__global__ __launch_bounds__(512, 4) void score_softmax(
    const float* __restrict__ qp,      // [1024][256] = Eq f32
    const ushort* __restrict__ kT,     // [32][4096][8] = Ek bf16
    const int*   __restrict__ mask,    // [8][512]
    const float* __restrict__ v,       // [256]
    float* __restrict__ out_w,         // [1024][512]
    ushort* __restrict__ wbf)          // [1024][512] bf16 weights
{
    __shared__ float scores[2][512];

    const int t = threadIdx.x;
    const int b  = blockIdx.x & 7;
    const int qg = blockIdx.x >> 3;    // 0..63
    const int rowbase = b * LQ_ + qg * 2;
    const int w = t >> 6, lane = t & 63;

    {
        const int m = t;               // 512 threads = 512 m
        const ushort* kbase = kT + ((size_t)b * 512 + m) * 8;
        const float* q0r = qp + (size_t)(rowbase + 0) * 256;
        const float* q1r = qp + (size_t)(rowbase + 1) * 256;
        float acc0 = 0.f, acc1 = 0.f;
#define QUAD(ACC, SQ, K, SV) { \
        const float u_ = fmaf(SQ.x, K.x, 1.f); \
        const float w_ = fmaf(SQ.y, K.y, 1.f); \
        const float y_ = fmaf(SQ.z, K.z, 1.f); \
        const float z_ = fmaf(SQ.w, K.w, 1.f); \
        const float d12_ = u_ * w_, d34_ = y_ * z_; \
        const float n12_ = fmaf(SV.y, u_, SV.x * w_); \
        const float n34_ = fmaf(SV.w, y_, SV.z * z_); \
        const float N_ = fmaf(n12_, d34_, n34_ * d12_); \
        ACC = fmaf(N_, __builtin_amdgcn_rcpf(d12_ * d34_), ACC); }
#pragma unroll 4
        for (int h8 = 0; h8 < 32; ++h8) {
            const ushort8 ku = *(const ushort8*)(kbase + (size_t)h8 * 32768);
            const float4 ka = {bf2f(ku[0]), bf2f(ku[1]), bf2f(ku[2]), bf2f(ku[3])};
            const float4 kb = {bf2f(ku[4]), bf2f(ku[5]), bf2f(ku[6]), bf2f(ku[7])};
            const float4 va = *(const float4*)(v + h8 * 8);
            const float4 vb = *(const float4*)(v + h8 * 8 + 4);
            const float4 s0a = *(const float4*)(q0r + h8 * 8);
            const float4 s0b = *(const float4*)(q0r + h8 * 8 + 4);
            const float4 s1a = *(const float4*)(q1r + h8 * 8);
            const float4 s1b = *(const float4*)(q1r + h8 * 8 + 4);
            QUAD(acc0, s0a, ka, va)
            QUAD(acc0, s0b, kb, vb)
            QUAD(acc1, s1a, ka, va)
            QUAD(acc1, s1b, kb, vb)
        }
#undef QUAD
        scores[0][m] = -2.f * acc0;
        scores[1][m] = -2.f * acc1;
    }
    __syncthreads();

    if (w < 2) {
        const int q = w, row = rowbase + q;
        float s[8], e[8];
        float mx = -INFINITY;
#pragma unroll
        for (int k = 0; k < 8; ++k) {
            const int m = lane + 64 * k;
            s[k] = mask[b * 512 + m] ? MASKVAL : scores[q][m];
            mx = fmaxf(mx, s[k]);
        }
#pragma unroll
        for (int off = 32; off >= 1; off >>= 1) mx = fmaxf(mx, __shfl_xor(mx, off));
        float sum = 0.0f;
#pragma unroll
        for (int k = 0; k < 8; ++k) {
            e[k] = __builtin_amdgcn_exp2f((s[k] - mx) * 1.44269504088896341f);
            sum += e[k];
        }
#pragma unroll
        for (int off = 32; off >= 1; off >>= 1) sum += __shfl_xor(sum, off);
        const float rs = __builtin_amdgcn_rcpf(sum);
#pragma unroll
        for (int k = 0; k < 8; ++k) {
            const int m = lane + 64 * k;
            const float wt = e[k] * rs;
            out_w[(size_t)row * 512 + m] = wt;
            wbf[(size_t)row * 512 + m] = f2bf(wt);
        }
    }
}

// ---------------- PV via MFMA (staged) ----------------
__global__ __launch_bounds__(256) void pv_mfma(
    const ushort* __restrict__ wbf,    // [1024][512] bf16
    const float* __restrict__ memory,  // [8][512][512]
    float* __restrict__ out_wm)        // [1024][512]
{
    __shared__ ushort As[PBM][PLDK];
    __shared__ ushort Bs[PBN][PLDK];

    const int b    = blockIdx.x & 7;
    const int rest = blockIdx.x >> 3;  // 0..63
    const int mt   = rest & 3;         // q-tile 0..3
    const int nt   = rest >> 2;        // d-tile 0..15
    const int n0   = nt * PBN;
    const ushort* A = wbf + ((size_t)b * LQ_ + mt * PBM) * 512;
    const float*  Bm = memory + (size_t)b * 512 * 512;

    const int t = threadIdx.x;
    const int lane = t & 63, w = t >> 6;
    const int wm = (w & 1) * 16, wn = (w >> 1) * 16;
    const int ar  = t >> 4;
    const int akq = t & 15;
    const int frow = lane & 15;
    const int fkof = (lane >> 4) * 8;

    f32x4 acc = {0.f, 0.f, 0.f, 0.f};

    for (int k0 = 0; k0 < 512; k0 += PBK) {
#pragma unroll
        for (int p = 0; p < 2; ++p) {
            const int row = ar + p * 16;
            *(ushort4*)&As[row][akq * 4] =
                *(const ushort4*)(A + (size_t)row * 512 + k0 + akq * 4);
        }
#pragma unroll
        for (int p = 0; p < 2; ++p) {
            const int L  = t + p * 256;
            const int kk = L >> 3;
            const int f4 = L & 7;
            const float4 w4 = *(const float4*)(Bm + (size_t)(k0 + kk) * 512 + n0 + f4 * 4);
            Bs[f4 * 4 + 0][kk] = f2bf(w4.x);
            Bs[f4 * 4 + 1][kk] = f2bf(w4.y);
            Bs[f4 * 4 + 2][kk] = f2bf(w4.z);
            Bs[f4 * 4 + 3][kk] = f2bf(w4.w);
        }
        __syncthreads();
#pragma unroll
        for (int ks = 0; ks < PBK; ks += 32) {
            bf16x8 a = *(const bf16x8*)&As[wm + frow][ks + fkof];
            bf16x8 b2 = *(const bf16x8*)&Bs[wn + frow][ks + fkof];
            acc = __builtin_amdgcn_mfma_f32_16x16x32_bf16(a, b2, acc, 0, 0, 0);
        }
        __syncthreads();
    }

    const int col  = n0 + wn + (lane & 15);
    const int rloc = wm + (lane >> 4) * 4;
    float* out = out_wm + ((size_t)b * LQ_ + mt * PBM) * 512;
#pragma unroll
    for (int r = 0; r < 4; ++r)
        out[(size_t)(rloc + r) * 512 + col] = acc[r];
}

extern "C" void kernel_launch(void* const* d_in, const int* in_sizes, int n_in,
                              void* d_out, int out_size, void* d_ws, size_t ws_size,
                              hipStream_t stream) {
    const float* query  = (const float*)d_in[0];
    const float* memory = (const float*)d_in[1];
    const int*   mask   = (const int*)  d_in[2];
    const float* Wq     = (const float*)d_in[3];
    const float* bq     = (const float*)d_in[4];
    const float* Wm     = (const float*)d_in[5];
    const float* v      = (const float*)d_in[6];

    float* out_wm = (float*)d_out;                         // [1024][512]
    float* out_w  = out_wm + (size_t)B_ * LQ_ * D_;        // [1024][512]

    float*  qp  = (float*)d_ws;                            // [1024][256] f32 = Eq
    ushort* kT  = (ushort*)(qp + (size_t)B_ * LQ_ * H_);   // [32][4096][8] bf16 = Ek
    ushort* wbf = kT + (size_t)32 * 4096 * 8;              // [1024][512] bf16

    hipLaunchKernelGGL(proj_mfma, dim3(160 * (H_ / PBN)), dim3(256), 0, stream,
                       query, memory, Wq, Wm, bq, qp, kT);
    hipLaunchKernelGGL(score_softmax, dim3(B_ * (LQ_ / 2)), dim3(512), 0, stream,
                       qp, kT, mask, v, out_w, wbf);
    hipLaunchKernelGGL(pv_mfma, dim3(8 * 64), dim3(256), 0, stream,
                       wbf, memory, out_wm);
}